// Round 1
// baseline (9565.606 us; speedup 1.0000x reference)
//
#include <hip/hip_runtime.h>
#include <math.h>

#define NG 8192          // graphs
#define NPG 32           // nodes per graph
#define NN (NG*NPG)      // 262144 nodes
#define NE (NN*4)        // 1048576 edges per side
#define EPG 128          // edges per graph
#define FIN 70
#define DIM 128
#define NB 4
#define DK 64
#define NREL 86

struct Smem {
  float x[NPG][DIM];        // current node features (input of layer / GAT output)
  float h2[NPG][DIM];       // x @ W  (also reused as u[4][128] in RESCAL)
  float wpan[16][DIM];      // staged W k-panel
  int   srcl[EPG];
  int   dstl[EPG];
  float alpha[EPG+NPG][2];  // per-(edge,head) alpha -> exp values
  float asrc[NPG][2];
  float adst[NPG][2];
  float den[NPG][2];
  float pl[NPG];
  float ql[NPG];
  float sval[NPG];
  float repr[2][NB][DIM];   // readouts, [side][layer][D]
  float keysl[NB][DK];
  float querl[NB][DK];
  float attw[NB*NB];
  float scl[2][NB];         // 1/clip(norm) of reprs
  float red[NB*NB];
};

__global__ __launch_bounds__(256) void relnorm_kernel(
    const float* __restrict__ re, float* __restrict__ outn) {
  int r = blockIdx.x;
  const float* row = re + (size_t)r * (DIM*DIM);
  float s = 0.f;
  for (int i = threadIdx.x; i < DIM*DIM; i += 256) { float v = row[i]; s += v*v; }
  for (int w = 1; w < 64; w <<= 1) s += __shfl_xor(s, w);
  __shared__ float sred[4];
  if ((threadIdx.x & 63) == 0) sred[threadIdx.x >> 6] = s;
  __syncthreads();
  if (threadIdx.x == 0) outn[r] = sqrtf(sred[0]+sred[1]+sred[2]+sred[3]);
}

__global__ __launch_bounds__(256, 3) void ssi_kernel(
    const float* __restrict__ xh, const float* __restrict__ xt,
    const int* __restrict__ eh, const int* __restrict__ et,
    const int* __restrict__ rels,
    const float* __restrict__ W0, const float* __restrict__ Wr,
    const float* __restrict__ att_src, const float* __restrict__ att_dst,
    const float* __restrict__ gat_b,
    const float* __restrict__ srw, const float* __restrict__ srb,
    const float* __restrict__ sroot,
    const float* __restrict__ nw, const float* __restrict__ nb2,
    const float* __restrict__ inw, const float* __restrict__ inb,
    const float* __restrict__ wqm, const float* __restrict__ wkm,
    const float* __restrict__ cob, const float* __restrict__ coa,
    const float* __restrict__ rel_emb, const float* __restrict__ rnorm,
    float* __restrict__ out)
{
  __shared__ Smem sm;
  const int t = threadIdx.x;
  const int g = blockIdx.x;
  const int n0 = g * NPG;

  for (int side = 0; side < 2; ++side) {
    const float* xin = side ? xt : xh;
    const int*   ed  = side ? et : eh;

    // ---- load edges (local ids) ----
    if (t < EPG) {
      sm.srcl[t] = ed[g*EPG + t] - n0;
      sm.dstl[t] = ed[NE + g*EPG + t] - n0;
    }
    // ---- input layernorm over FIN=70 ----
    {
      int n = t >> 3, j = t & 7;
      float s = 0.f, s2 = 0.f;
      for (int f = j; f < FIN; f += 8) {
        float v = xin[(size_t)(n0+n)*FIN + f];
        s += v; s2 += v*v;
      }
      for (int w = 1; w < 8; w <<= 1) { s += __shfl_xor(s, w); s2 += __shfl_xor(s2, w); }
      float mu  = s * (1.f/FIN);
      float var = s2 * (1.f/FIN) - mu*mu;
      float inv = rsqrtf(var + 1e-5f);
      for (int f = j; f < FIN; f += 8) {
        float v = xin[(size_t)(n0+n)*FIN + f];
        sm.x[n][f] = (v - mu) * inv * inw[f] + inb[f];
      }
      if (j == 0) { sm.x[n][70] = 0.f; sm.x[n][71] = 0.f; }  // K-pad to 72
    }
    __syncthreads();

    for (int li = 0; li < NB; ++li) {
      const float* W = (li == 0) ? W0 : (Wr + (size_t)(li-1)*DIM*DIM);
      const int K    = (li == 0) ? FIN : DIM;
      const int Kpad = (li == 0) ? 72  : DIM;

      // ---- C1: h2 = x @ W  (4 nodes x 4 cols per thread, W via LDS panel) ----
      {
        const int c0  = (t & 31) * 4;
        const int nd0 = (t >> 5) * 4;
        float acc[4][4];
        #pragma unroll
        for (int m = 0; m < 4; ++m)
          #pragma unroll
          for (int q = 0; q < 4; ++q) acc[m][q] = 0.f;

        for (int kp = 0; kp < Kpad; kp += 16) {
          int kpn = min(16, Kpad - kp);
          __syncthreads();
          for (int idx = t; idx < kpn*32; idx += 256) {
            int kk = idx >> 5, cc = (idx & 31) * 4;
            int kg = kp + kk;
            float4 wv;
            if (kg < K) wv = *(const float4*)(W + (size_t)kg*DIM + cc);
            else        wv = make_float4(0.f,0.f,0.f,0.f);
            *(float4*)&sm.wpan[kk][cc] = wv;
          }
          __syncthreads();
          for (int kk = 0; kk < kpn; kk += 4) {
            float4 xa[4], wa[4];
            #pragma unroll
            for (int m = 0; m < 4; ++m) xa[m] = *(const float4*)&sm.x[nd0+m][kp+kk];
            #pragma unroll
            for (int q = 0; q < 4; ++q) wa[q] = *(const float4*)&sm.wpan[kk+q][c0];
            #pragma unroll
            for (int m = 0; m < 4; ++m) {
              const float* xm = (const float*)&xa[m];
              #pragma unroll
              for (int q = 0; q < 4; ++q) {
                const float* wp = (const float*)&wa[q];
                float xv = xm[q];
                acc[m][0] += xv * wp[0];
                acc[m][1] += xv * wp[1];
                acc[m][2] += xv * wp[2];
                acc[m][3] += xv * wp[3];
              }
            }
          }
        }
        #pragma unroll
        for (int m = 0; m < 4; ++m)
          *(float4*)&sm.h2[nd0+m][c0] =
              make_float4(acc[m][0], acc[m][1], acc[m][2], acc[m][3]);
      }
      __syncthreads();

      // ---- C2: a_src/a_dst per (node, head) ----
      {
        int n = t >> 3, hd = (t >> 2) & 1, j = t & 3;
        const float* as = att_src + ((size_t)li*2 + hd)*64;
        const float* ad = att_dst + ((size_t)li*2 + hd)*64;
        float ss = 0.f, sd = 0.f;
        int cb = hd*64 + j*16;
        #pragma unroll
        for (int u = 0; u < 16; ++u) {
          float hv = sm.h2[n][cb+u];
          ss += hv * as[j*16+u];
          sd += hv * ad[j*16+u];
        }
        ss += __shfl_xor(ss,1); ss += __shfl_xor(ss,2);
        sd += __shfl_xor(sd,1); sd += __shfl_xor(sd,2);
        if (j == 0) { sm.asrc[n][hd] = ss; sm.adst[n][hd] = sd; }
      }
      __syncthreads();

      // ---- C3: alpha = leaky_relu(a_src[s] + a_dst[d]) for 128 edges + 32 loops ----
      if (t < EPG + NPG) {
        int s = (t < EPG) ? sm.srcl[t] : (t - EPG);
        int d = (t < EPG) ? sm.dstl[t] : (t - EPG);
        #pragma unroll
        for (int hd = 0; hd < 2; ++hd) {
          float a = sm.asrc[s][hd] + sm.adst[d][hd];
          sm.alpha[t][hd] = (a > 0.f) ? a : 0.2f*a;
        }
      }
      __syncthreads();

      // ---- C4: per-(dst,head) max, exp, denom ----
      if (t < 64) {
        int d = t >> 1, hd = t & 1;
        float m = -1e30f;
        for (int e = 0; e < EPG+NPG; ++e) {
          int de = (e < EPG) ? sm.dstl[e] : (e - EPG);
          if (de == d) m = fmaxf(m, sm.alpha[e][hd]);
        }
        float s = 0.f;
        for (int e = 0; e < EPG+NPG; ++e) {
          int de = (e < EPG) ? sm.dstl[e] : (e - EPG);
          if (de == d) {
            float ex = expf(sm.alpha[e][hd] - m);
            sm.alpha[e][hd] = ex;
            s += ex;
          }
        }
        sm.den[d][hd] = s;
      }
      __syncthreads();

      // ---- C5: x = segment_sum(h2[src]*w) + bias ----
      {
        int n = t >> 3, cg = t & 7;
        int c0 = cg * 16;
        int hd = c0 >> 6;
        float acc[16];
        #pragma unroll
        for (int u = 0; u < 16; ++u) acc[u] = 0.f;
        float dinv = 1.f / (sm.den[n][hd] + 1e-16f);
        for (int e = 0; e < EPG+NPG; ++e) {
          int de = (e < EPG) ? sm.dstl[e] : (e - EPG);
          if (de == n) {
            int se = (e < EPG) ? sm.srcl[e] : (e - EPG);
            float w = sm.alpha[e][hd] * dinv;
            #pragma unroll
            for (int q = 0; q < 4; ++q) {
              float4 hv = *(const float4*)&sm.h2[se][c0 + 4*q];
              acc[4*q+0] += w * hv.x;
              acc[4*q+1] += w * hv.y;
              acc[4*q+2] += w * hv.z;
              acc[4*q+3] += w * hv.w;
            }
          }
        }
        #pragma unroll
        for (int u = 0; u < 16; ++u)
          sm.x[n][c0+u] = acc[u] + gat_b[(size_t)li*DIM + c0 + u];
      }
      __syncthreads();

      // ---- C6a: p = x.rw, q = x.root_w per node ----
      {
        int n = t >> 3, j = t & 7;
        const float* rw = srw   + (size_t)li*DIM;
        const float* ro = sroot + (size_t)li*DIM;
        float p = 0.f, q = 0.f;
        #pragma unroll
        for (int u = 0; u < 16; ++u) {
          float xv = sm.x[n][j*16+u];
          p += xv * rw[j*16+u];
          q += xv * ro[j*16+u];
        }
        for (int w = 1; w < 8; w <<= 1) { p += __shfl_xor(p,w); q += __shfl_xor(q,w); }
        if (j == 0) { sm.pl[n] = p; sm.ql[n] = q; }
      }
      __syncthreads();

      // ---- C6b: score + per-graph softmax (32 nodes, wave 0) ----
      if (t < NPG) {
        int n = t;
        float s = 0.f;
        for (int e = 0; e < EPG; ++e)
          if (sm.dstl[e] == n) s += sm.pl[sm.srcl[e]];
        s += srb[li] + sm.ql[n];
        float m = s;
        for (int w = 1; w < 32; w <<= 1) m = fmaxf(m, __shfl_xor(m, w));
        float ex = expf(s - m);
        float dn = ex;
        for (int w = 1; w < 32; w <<= 1) dn += __shfl_xor(dn, w);
        sm.sval[n] = ex / (dn + 1e-16f);
      }
      __syncthreads();

      // ---- C6c: repr[c] = sum_n x[n][c]*sval[n] ----
      if (t < DIM) {
        float a = 0.f;
        for (int n = 0; n < NPG; ++n) a += sm.x[n][t] * sm.sval[n];
        sm.repr[side][li][t] = a;
      }
      __syncthreads();

      // ---- C7: x = elu(layernorm(x)) (skipped for last layer) ----
      if (li < NB-1) {
        int n = t >> 3, j = t & 7;
        float s = 0.f, s2 = 0.f;
        #pragma unroll
        for (int u = 0; u < 16; ++u) {
          float v = sm.x[n][j*16+u];
          s += v; s2 += v*v;
        }
        for (int w = 1; w < 8; w <<= 1) { s += __shfl_xor(s,w); s2 += __shfl_xor(s2,w); }
        float mu  = s * (1.f/DIM);
        float var = s2 * (1.f/DIM) - mu*mu;
        float inv = rsqrtf(var + 1e-5f);
        const float* wv = nw  + (size_t)li*DIM;
        const float* bv = nb2 + (size_t)li*DIM;
        #pragma unroll
        for (int u = 0; u < 16; ++u) {
          int c = j*16+u;
          float v = (sm.x[n][c] - mu) * inv * wv[c] + bv[c];
          sm.x[n][c] = (v > 0.f) ? v : expm1f(v);
        }
        __syncthreads();
      }
    }  // layer loop
  }  // side loop

  // ---- F1: keys = rh @ wk, queries = rt @ wq (one wave per block-row i) ----
  {
    int i2 = t >> 6, k = t & 63;
    float ak = 0.f, aq = 0.f;
    for (int d = 0; d < DIM; ++d) {
      ak += sm.repr[0][i2][d] * wkm[(size_t)d*DK + k];
      aq += sm.repr[1][i2][d] * wqm[(size_t)d*DK + k];
    }
    sm.keysl[i2][k] = ak;
    sm.querl[i2][k] = aq;
  }
  // ---- F2b: repr norms (reads repr only; disjoint writes) ----
  {
    int sd = t >> 7, i = (t >> 5) & 3, j2 = t & 31;
    float s = 0.f;
    #pragma unroll
    for (int u = 0; u < 4; ++u) {
      float v = sm.repr[sd][i][j2*4+u];
      s += v*v;
    }
    for (int w = 1; w < 32; w <<= 1) s += __shfl_xor(s, w);
    if (j2 == 0) sm.scl[sd][i] = 1.f / fmaxf(sqrtf(s), 1e-12f);
  }
  __syncthreads();

  // ---- F2: att[i][j] = sum_k tanh(keys[i][k]+queries[j][k]+cob[k])*coa[k] ----
  {
    int pair = t >> 4, kk = t & 15;
    int i = pair >> 2, j = pair & 3;
    float a = 0.f;
    #pragma unroll
    for (int u = 0; u < 4; ++u) {
      int k = kk*4+u;
      a += tanhf(sm.keysl[i][k] + sm.querl[j][k] + cob[k]) * coa[k];
    }
    for (int w = 1; w < 16; w <<= 1) a += __shfl_xor(a, w);
    if (kk == 0) sm.attw[pair] = a;
  }
  // ---- F3: u[i][:] = repr_h[i] @ r_raw  (into h2 rows 0..3) ----
  int rel = rels[g];
  if (t < DIM) {
    const float* rr = rel_emb + (size_t)rel * (DIM*DIM);
    float a0=0.f, a1=0.f, a2=0.f, a3=0.f;
    for (int d = 0; d < DIM; ++d) {
      float rv = rr[(size_t)d*DIM + t];
      a0 += sm.repr[0][0][d] * rv;
      a1 += sm.repr[0][1][d] * rv;
      a2 += sm.repr[0][2][d] * rv;
      a3 += sm.repr[0][3][d] * rv;
    }
    sm.h2[0][t]=a0; sm.h2[1][t]=a1; sm.h2[2][t]=a2; sm.h2[3][t]=a3;
  }
  __syncthreads();

  // ---- F4: scores[i][j] + weighted sum ----
  {
    float rninv = 1.f / fmaxf(rnorm[rel], 1e-12f);
    int pair = t >> 4, kk = t & 15;
    int i = pair >> 2, j = pair & 3;
    float a = 0.f;
    #pragma unroll
    for (int u = 0; u < 8; ++u) {
      int e = kk*8+u;
      a += sm.h2[i][e] * sm.repr[1][j][e];
    }
    for (int w = 1; w < 16; w <<= 1) a += __shfl_xor(a, w);
    if (kk == 0)
      sm.red[pair] = sm.attw[pair] * a * sm.scl[0][i] * sm.scl[1][j] * rninv;
  }
  __syncthreads();
  if (t == 0) {
    float s = 0.f;
    for (int p = 0; p < NB*NB; ++p) s += sm.red[p];
    out[g] = s;
  }
}

extern "C" void kernel_launch(void* const* d_in, const int* in_sizes, int n_in,
                              void* d_out, int out_size, void* d_ws, size_t ws_size,
                              hipStream_t stream) {
  const float* xh      = (const float*)d_in[0];
  const float* xt      = (const float*)d_in[1];
  const int*   eh      = (const int*)d_in[2];
  const int*   et      = (const int*)d_in[3];
  // d_in[4] = batch (structurally n>>5; unused)
  const int*   rels    = (const int*)d_in[5];
  const float* W0      = (const float*)d_in[6];
  const float* Wr      = (const float*)d_in[7];
  const float* att_src = (const float*)d_in[8];
  const float* att_dst = (const float*)d_in[9];
  const float* gat_b   = (const float*)d_in[10];
  const float* srw     = (const float*)d_in[11];
  const float* srb     = (const float*)d_in[12];
  const float* sroot   = (const float*)d_in[13];
  const float* nw      = (const float*)d_in[14];
  const float* nb2     = (const float*)d_in[15];
  const float* inw     = (const float*)d_in[16];
  const float* inb     = (const float*)d_in[17];
  const float* wqm     = (const float*)d_in[18];
  const float* wkm     = (const float*)d_in[19];
  const float* cob     = (const float*)d_in[20];
  const float* coa     = (const float*)d_in[21];
  const float* rel_emb = (const float*)d_in[22];
  float* out   = (float*)d_out;
  float* rnorm = (float*)d_ws;   // 86 floats

  relnorm_kernel<<<NREL, 256, 0, stream>>>(rel_emb, rnorm);
  ssi_kernel<<<NG, 256, 0, stream>>>(xh, xt, eh, et, rels, W0, Wr, att_src, att_dst,
      gat_b, srw, srb, sroot, nw, nb2, inw, inb, wqm, wkm, cob, coa, rel_emb,
      rnorm, out);
}

// Round 2
// 3736.885 us; speedup vs baseline: 2.5598x; 2.5598x over previous
//
#include <hip/hip_runtime.h>
#include <math.h>

#define NG 8192          // graphs
#define NPG 32           // nodes per graph
#define NN (NG*NPG)      // 262144 nodes
#define NE (NN*4)        // 1048576 edges per side
#define EPG 128          // edges per graph
#define NEL (EPG+NPG)    // edges + self loops
#define FIN 70
#define DIM 128
#define XS 136           // padded row stride (8 mod 32 banks)
#define NB 4
#define DK 64
#define NREL 86

struct Smem {
  float x[NPG][XS];         // node features, padded stride
  float h2[NPG][XS];        // x @ W, padded stride (reused as u[4][*] in RESCAL)
  union {
    float wpan[16][DIM];    // staged W k-panel (C1)
    float P[2][NPG][NPG];   // attention matrix [head][src][dst] (C3b-C5)
  } u;
  int   srcl[EPG];
  int   dstl[EPG];
  float alpha[2][NEL];      // [head][edge]
  float asrc[NPG][2];
  float adst[NPG][2];
  float den[NPG][2];        // 1/(sum+eps) per (dst,head)
  float mh[2];
  float wred[4][2];
  float pl[NPG];
  float ql[NPG];
  float sval[NPG];
  float sacc[NPG];
  float repr[2][NB][DIM];   // readouts [side][layer][D]
  float keysl[NB][DK];
  float querl[NB][DK];
  float attw[NB*NB];
  float scl[2][NB];
  float red[NB*NB];
};

__global__ __launch_bounds__(256) void relnorm_kernel(
    const float* __restrict__ re, float* __restrict__ outn) {
  int r = blockIdx.x;
  const float* row = re + (size_t)r * (DIM*DIM);
  float s = 0.f;
  for (int i = threadIdx.x; i < DIM*DIM; i += 256) { float v = row[i]; s += v*v; }
  for (int w = 1; w < 64; w <<= 1) s += __shfl_xor(s, w);
  __shared__ float sred[4];
  if ((threadIdx.x & 63) == 0) sred[threadIdx.x >> 6] = s;
  __syncthreads();
  if (threadIdx.x == 0) outn[r] = sqrtf(sred[0]+sred[1]+sred[2]+sred[3]);
}

__global__ __launch_bounds__(256, 3) void ssi_kernel(
    const float* __restrict__ xh, const float* __restrict__ xt,
    const int* __restrict__ eh, const int* __restrict__ et,
    const int* __restrict__ rels,
    const float* __restrict__ W0, const float* __restrict__ Wr,
    const float* __restrict__ att_src, const float* __restrict__ att_dst,
    const float* __restrict__ gat_b,
    const float* __restrict__ srw, const float* __restrict__ srb,
    const float* __restrict__ sroot,
    const float* __restrict__ nw, const float* __restrict__ nb2,
    const float* __restrict__ inw, const float* __restrict__ inb,
    const float* __restrict__ wqm, const float* __restrict__ wkm,
    const float* __restrict__ cob, const float* __restrict__ coa,
    const float* __restrict__ rel_emb, const float* __restrict__ rnorm,
    float* __restrict__ out)
{
  __shared__ Smem sm;
  const int t = threadIdx.x;
  const int g = blockIdx.x;
  const int n0 = g * NPG;

  for (int side = 0; side < 2; ++side) {
    const float* xin = side ? xt : xh;
    const int*   ed  = side ? et : eh;

    // ---- load edges (local ids) ----
    if (t < EPG) {
      sm.srcl[t] = ed[g*EPG + t] - n0;
      sm.dstl[t] = ed[NE + g*EPG + t] - n0;
    }
    // ---- input layernorm over FIN=70 ----
    {
      int n = t >> 3, j = t & 7;
      float s = 0.f, s2 = 0.f;
      for (int f = j; f < FIN; f += 8) {
        float v = xin[(size_t)(n0+n)*FIN + f];
        s += v; s2 += v*v;
      }
      for (int w = 1; w < 8; w <<= 1) { s += __shfl_xor(s, w); s2 += __shfl_xor(s2, w); }
      float mu  = s * (1.f/FIN);
      float var = s2 * (1.f/FIN) - mu*mu;
      float inv = rsqrtf(var + 1e-5f);
      for (int f = j; f < FIN; f += 8) {
        float v = xin[(size_t)(n0+n)*FIN + f];
        sm.x[n][f] = (v - mu) * inv * inw[f] + inb[f];
      }
      if (j == 0) { sm.x[n][70] = 0.f; sm.x[n][71] = 0.f; }  // K-pad to 72
    }
    __syncthreads();

    for (int li = 0; li < NB; ++li) {
      const float* W = (li == 0) ? W0 : (Wr + (size_t)(li-1)*DIM*DIM);
      const int K    = (li == 0) ? FIN : DIM;
      const int Kpad = (li == 0) ? 72  : DIM;

      // ---- C1: h2 = x @ W  (4 nodes x 4 cols per thread, W via LDS panel) ----
      {
        const int c0  = (t & 31) * 4;
        const int nd0 = (t >> 5) * 4;
        float acc[4][4];
        #pragma unroll
        for (int m = 0; m < 4; ++m)
          #pragma unroll
          for (int q = 0; q < 4; ++q) acc[m][q] = 0.f;

        for (int kp = 0; kp < Kpad; kp += 16) {
          int kpn = min(16, Kpad - kp);
          __syncthreads();
          for (int idx = t; idx < kpn*32; idx += 256) {
            int kk = idx >> 5, cc = (idx & 31) * 4;
            int kg = kp + kk;
            float4 wv;
            if (kg < K) wv = *(const float4*)(W + (size_t)kg*DIM + cc);
            else        wv = make_float4(0.f,0.f,0.f,0.f);
            *(float4*)&sm.u.wpan[kk][cc] = wv;
          }
          __syncthreads();
          for (int kk = 0; kk < kpn; kk += 4) {
            float4 xa[4], wa[4];
            #pragma unroll
            for (int m = 0; m < 4; ++m) xa[m] = *(const float4*)&sm.x[nd0+m][kp+kk];
            #pragma unroll
            for (int q = 0; q < 4; ++q) wa[q] = *(const float4*)&sm.u.wpan[kk+q][c0];
            #pragma unroll
            for (int m = 0; m < 4; ++m) {
              const float* xm = (const float*)&xa[m];
              #pragma unroll
              for (int q = 0; q < 4; ++q) {
                const float* wp = (const float*)&wa[q];
                float xv = xm[q];
                acc[m][0] += xv * wp[0];
                acc[m][1] += xv * wp[1];
                acc[m][2] += xv * wp[2];
                acc[m][3] += xv * wp[3];
              }
            }
          }
        }
        #pragma unroll
        for (int m = 0; m < 4; ++m)
          *(float4*)&sm.h2[nd0+m][c0] =
              make_float4(acc[m][0], acc[m][1], acc[m][2], acc[m][3]);
      }
      __syncthreads();

      // ---- C2: a_src/a_dst per (node, head); also zero P (wpan now free) ----
      {
        int n = t >> 3, hd = (t >> 2) & 1, j = t & 3;
        const float* as = att_src + ((size_t)li*2 + hd)*64;
        const float* ad = att_dst + ((size_t)li*2 + hd)*64;
        float ss = 0.f, sd = 0.f;
        #pragma unroll
        for (int uu = 0; uu < 16; ++uu) {
          int cl = uu*4 + j;               // column within head, stride-4 interleave
          float hv = sm.h2[n][hd*64 + cl];
          ss += hv * as[cl];
          sd += hv * ad[cl];
        }
        ss += __shfl_xor(ss,1); ss += __shfl_xor(ss,2);
        sd += __shfl_xor(sd,1); sd += __shfl_xor(sd,2);
        if (j == 0) { sm.asrc[n][hd] = ss; sm.adst[n][hd] = sd; }
        float4* Pf = (float4*)&sm.u.P[0][0][0];
        float4 z4 = make_float4(0.f,0.f,0.f,0.f);
        Pf[t*2] = z4; Pf[t*2+1] = z4;
      }
      __syncthreads();

      // ---- C3: alpha = leaky_relu(a_src[s] + a_dst[d]) for 160 entries ----
      if (t < NEL) {
        int s = (t < EPG) ? sm.srcl[t] : (t - EPG);
        int d = (t < EPG) ? sm.dstl[t] : (t - EPG);
        #pragma unroll
        for (int hd = 0; hd < 2; ++hd) {
          float a = sm.asrc[s][hd] + sm.adst[d][hd];
          sm.alpha[hd][t] = (a > 0.f) ? a : 0.2f*a;
        }
      }
      __syncthreads();

      // ---- C4a: per-head block max (softmax shift; scale-invariant) ----
      {
        float a0 = (t < NEL) ? sm.alpha[0][t] : -1e30f;
        float a1 = (t < NEL) ? sm.alpha[1][t] : -1e30f;
        for (int w = 1; w < 64; w <<= 1) {
          a0 = fmaxf(a0, __shfl_xor(a0, w));
          a1 = fmaxf(a1, __shfl_xor(a1, w));
        }
        if ((t & 63) == 0) { sm.wred[t>>6][0] = a0; sm.wred[t>>6][1] = a1; }
      }
      __syncthreads();
      if (t < 2) {
        sm.mh[t] = fmaxf(fmaxf(sm.wred[0][t], sm.wred[1][t]),
                         fmaxf(sm.wred[2][t], sm.wred[3][t]));
      }
      __syncthreads();

      // ---- C4b: scatter exp into P[h][s][d] ----
      if (t < NEL) {
        int s = (t < EPG) ? sm.srcl[t] : (t - EPG);
        int d = (t < EPG) ? sm.dstl[t] : (t - EPG);
        float e0 = expf(sm.alpha[0][t] - sm.mh[0]);
        float e1 = expf(sm.alpha[1][t] - sm.mh[1]);
        atomicAdd(&sm.u.P[0][s][d], e0);
        atomicAdd(&sm.u.P[1][s][d], e1);
      }
      __syncthreads();

      // ---- C4c: den[d][h] = 1/(col-sum + eps) ----
      if (t < 64) {
        int d = t & 31, hd = t >> 5;
        float s = 0.f;
        for (int ss = 0; ss < NPG; ++ss) s += sm.u.P[hd][ss][d];
        sm.den[d][hd] = 1.f / (s + 1e-16f);
      }
      __syncthreads();

      // ---- C5: x = (P^T h2) * dinv + bias  (dense, 4x4 tile like C1) ----
      {
        const int c0  = (t & 31) * 4;
        const int nd0 = (t >> 5) * 4;
        const int h   = c0 >> 6;
        float acc[4][4];
        #pragma unroll
        for (int m = 0; m < 4; ++m)
          #pragma unroll
          for (int q = 0; q < 4; ++q) acc[m][q] = 0.f;
        for (int s = 0; s < NPG; ++s) {
          float4 wv = *(const float4*)&sm.u.P[h][s][nd0];
          float4 hv = *(const float4*)&sm.h2[s][c0];
          const float* wp = (const float*)&wv;
          const float* hp = (const float*)&hv;
          #pragma unroll
          for (int m = 0; m < 4; ++m) {
            float wm = wp[m];
            acc[m][0] += wm * hp[0];
            acc[m][1] += wm * hp[1];
            acc[m][2] += wm * hp[2];
            acc[m][3] += wm * hp[3];
          }
        }
        float4 bv = *(const float4*)&gat_b[(size_t)li*DIM + c0];
        #pragma unroll
        for (int m = 0; m < 4; ++m) {
          float dv = sm.den[nd0+m][h];
          *(float4*)&sm.x[nd0+m][c0] = make_float4(
              acc[m][0]*dv + bv.x, acc[m][1]*dv + bv.y,
              acc[m][2]*dv + bv.z, acc[m][3]*dv + bv.w);
        }
      }
      __syncthreads();

      // ---- C6a: p = x.rw, q = x.root_w per node; zero sacc ----
      {
        int n = t >> 3, j = t & 7;
        const float* rw = srw   + (size_t)li*DIM;
        const float* ro = sroot + (size_t)li*DIM;
        float p = 0.f, q = 0.f;
        #pragma unroll
        for (int uu = 0; uu < 16; ++uu) {
          int c = uu*8 + j;
          float xv = sm.x[n][c];
          p += xv * rw[c];
          q += xv * ro[c];
        }
        for (int w = 1; w < 8; w <<= 1) { p += __shfl_xor(p,w); q += __shfl_xor(q,w); }
        if (j == 0) { sm.pl[n] = p; sm.ql[n] = q; }
        if (t < NPG) sm.sacc[t] = 0.f;
      }
      __syncthreads();

      // ---- C6b-1: scatter aggr scores ----
      if (t < EPG) atomicAdd(&sm.sacc[sm.dstl[t]], sm.pl[sm.srcl[t]]);
      __syncthreads();

      // ---- C6b-2: per-graph softmax over 32 nodes ----
      if (t < NPG) {
        float s = sm.sacc[t] + srb[li] + sm.ql[t];
        float m = s;
        for (int w = 1; w < 32; w <<= 1) m = fmaxf(m, __shfl_xor(m, w));
        float ex = expf(s - m);
        float dn = ex;
        for (int w = 1; w < 32; w <<= 1) dn += __shfl_xor(dn, w);
        sm.sval[t] = ex / (dn + 1e-16f);
      }
      __syncthreads();

      // ---- C6c: repr[c] = sum_n x[n][c]*sval[n] ----
      if (t < DIM) {
        float a = 0.f;
        for (int n = 0; n < NPG; ++n) a += sm.x[n][t] * sm.sval[n];
        sm.repr[side][li][t] = a;
      }
      __syncthreads();

      // ---- C7: x = elu(layernorm(x)) (skipped for last layer) ----
      if (li < NB-1) {
        int n = t >> 3, j = t & 7;
        float s = 0.f, s2 = 0.f;
        #pragma unroll
        for (int uu = 0; uu < 16; ++uu) {
          float v = sm.x[n][uu*8 + j];
          s += v; s2 += v*v;
        }
        for (int w = 1; w < 8; w <<= 1) { s += __shfl_xor(s,w); s2 += __shfl_xor(s2,w); }
        float mu  = s * (1.f/DIM);
        float var = s2 * (1.f/DIM) - mu*mu;
        float inv = rsqrtf(var + 1e-5f);
        const float* wv = nw  + (size_t)li*DIM;
        const float* bv = nb2 + (size_t)li*DIM;
        #pragma unroll
        for (int uu = 0; uu < 16; ++uu) {
          int c = uu*8 + j;
          float v = (sm.x[n][c] - mu) * inv * wv[c] + bv[c];
          sm.x[n][c] = (v > 0.f) ? v : expm1f(v);
        }
        __syncthreads();
      }
    }  // layer loop
  }  // side loop

  // ---- F1: keys = rh @ wk, queries = rt @ wq ----
  {
    int i2 = t >> 6, k = t & 63;
    float ak = 0.f, aq = 0.f;
    for (int d = 0; d < DIM; ++d) {
      ak += sm.repr[0][i2][d] * wkm[(size_t)d*DK + k];
      aq += sm.repr[1][i2][d] * wqm[(size_t)d*DK + k];
    }
    sm.keysl[i2][k] = ak;
    sm.querl[i2][k] = aq;
  }
  // ---- F2b: repr norms ----
  {
    int sd = t >> 7, i = (t >> 5) & 3, j2 = t & 31;
    float s = 0.f;
    #pragma unroll
    for (int uu = 0; uu < 4; ++uu) {
      float v = sm.repr[sd][i][j2*4+uu];
      s += v*v;
    }
    for (int w = 1; w < 32; w <<= 1) s += __shfl_xor(s, w);
    if (j2 == 0) sm.scl[sd][i] = 1.f / fmaxf(sqrtf(s), 1e-12f);
  }
  __syncthreads();

  // ---- F2: att[i][j] ----
  {
    int pair = t >> 4, kk = t & 15;
    int i = pair >> 2, j = pair & 3;
    float a = 0.f;
    #pragma unroll
    for (int uu = 0; uu < 4; ++uu) {
      int k = kk*4+uu;
      a += tanhf(sm.keysl[i][k] + sm.querl[j][k] + cob[k]) * coa[k];
    }
    for (int w = 1; w < 16; w <<= 1) a += __shfl_xor(a, w);
    if (kk == 0) sm.attw[pair] = a;
  }
  // ---- F3: u[i][:] = repr_h[i] @ r_raw  (into h2 rows 0..3) ----
  int rel = rels[g];
  if (t < DIM) {
    const float* rr = rel_emb + (size_t)rel * (DIM*DIM);
    float a0=0.f, a1=0.f, a2=0.f, a3=0.f;
    for (int d = 0; d < DIM; ++d) {
      float rv = rr[(size_t)d*DIM + t];
      a0 += sm.repr[0][0][d] * rv;
      a1 += sm.repr[0][1][d] * rv;
      a2 += sm.repr[0][2][d] * rv;
      a3 += sm.repr[0][3][d] * rv;
    }
    sm.h2[0][t]=a0; sm.h2[1][t]=a1; sm.h2[2][t]=a2; sm.h2[3][t]=a3;
  }
  __syncthreads();

  // ---- F4: scores + weighted sum ----
  {
    float rninv = 1.f / fmaxf(rnorm[rel], 1e-12f);
    int pair = t >> 4, kk = t & 15;
    int i = pair >> 2, j = pair & 3;
    float a = 0.f;
    #pragma unroll
    for (int uu = 0; uu < 8; ++uu) {
      int e = kk*8+uu;
      a += sm.h2[i][e] * sm.repr[1][j][e];
    }
    for (int w = 1; w < 16; w <<= 1) a += __shfl_xor(a, w);
    if (kk == 0)
      sm.red[pair] = sm.attw[pair] * a * sm.scl[0][i] * sm.scl[1][j] * rninv;
  }
  __syncthreads();
  if (t == 0) {
    float s = 0.f;
    for (int p = 0; p < NB*NB; ++p) s += sm.red[p];
    out[g] = s;
  }
}

extern "C" void kernel_launch(void* const* d_in, const int* in_sizes, int n_in,
                              void* d_out, int out_size, void* d_ws, size_t ws_size,
                              hipStream_t stream) {
  const float* xh      = (const float*)d_in[0];
  const float* xt      = (const float*)d_in[1];
  const int*   eh      = (const int*)d_in[2];
  const int*   et      = (const int*)d_in[3];
  // d_in[4] = batch (structurally n>>5; unused)
  const int*   rels    = (const int*)d_in[5];
  const float* W0      = (const float*)d_in[6];
  const float* Wr      = (const float*)d_in[7];
  const float* att_src = (const float*)d_in[8];
  const float* att_dst = (const float*)d_in[9];
  const float* gat_b   = (const float*)d_in[10];
  const float* srw     = (const float*)d_in[11];
  const float* srb     = (const float*)d_in[12];
  const float* sroot   = (const float*)d_in[13];
  const float* nw      = (const float*)d_in[14];
  const float* nb2     = (const float*)d_in[15];
  const float* inw     = (const float*)d_in[16];
  const float* inb     = (const float*)d_in[17];
  const float* wqm     = (const float*)d_in[18];
  const float* wkm     = (const float*)d_in[19];
  const float* cob     = (const float*)d_in[20];
  const float* coa     = (const float*)d_in[21];
  const float* rel_emb = (const float*)d_in[22];
  float* out   = (float*)d_out;
  float* rnorm = (float*)d_ws;   // 86 floats

  relnorm_kernel<<<NREL, 256, 0, stream>>>(rel_emb, rnorm);
  ssi_kernel<<<NG, 256, 0, stream>>>(xh, xt, eh, et, rels, W0, Wr, att_src, att_dst,
      gat_b, srw, srb, sroot, nw, nb2, inw, inb, wqm, wkm, cob, coa, rel_emb,
      rnorm, out);
}